// Round 1
// baseline (460.507 us; speedup 1.0000x reference)
//
#include <hip/hip_runtime.h>

#define D_DIM 1024
#define N_INNER 4096
#define NEXP 8
#define T_TOK 8192
#define EPSV 1e-6f

typedef __attribute__((ext_vector_type(4))) float f32x4;
typedef __bf16 bf16x8 __attribute__((ext_vector_type(8)));

typedef const __attribute__((address_space(1))) void gvoid_t;
typedef __attribute__((address_space(3))) void lvoid_t;

static __device__ __forceinline__ unsigned short f2bf(float f) {
    unsigned int u = __float_as_uint(f);
    u = u + 0x7fffu + ((u >> 16) & 1u);   // round-to-nearest-even
    return (unsigned short)(u >> 16);
}

// ---------------- gating: one wave per token ----------------
__global__ __launch_bounds__(256) void k_gate(const float* __restrict__ x,
                                              const float* __restrict__ Wg,
                                              const float* __restrict__ bg,
                                              int* __restrict__ top1,
                                              float* __restrict__ score) {
    __shared__ float wgT[NEXP * D_DIM];      // transposed gate weights, 32 KB
    int tid = threadIdx.x;
    for (int i = tid; i < NEXP * D_DIM; i += 256)
        wgT[(i & 7) * D_DIM + (i >> 3)] = Wg[i];
    __syncthreads();

    int wid = tid >> 6, lane = tid & 63;
    int t = blockIdx.x * 4 + wid;
    float acc[8] = {0.f, 0.f, 0.f, 0.f, 0.f, 0.f, 0.f, 0.f};
    const float* xp = x + (size_t)t * D_DIM + lane;
    for (int c = 0; c < D_DIM / 64; ++c) {
        float xv = xp[c * 64];
#pragma unroll
        for (int e = 0; e < 8; ++e) acc[e] += xv * wgT[e * D_DIM + c * 64 + lane];
    }
#pragma unroll
    for (int e = 0; e < 8; ++e) {
        float v = acc[e];
        for (int o = 32; o; o >>= 1) v += __shfl_xor(v, o);
        acc[e] = v;
    }
    if (lane == 0) {
        float mx = -1e30f;
#pragma unroll
        for (int e = 0; e < 8; ++e) { acc[e] += bg[e]; mx = fmaxf(mx, acc[e]); }
        float p[8], s = 0.f;
#pragma unroll
        for (int e = 0; e < 8; ++e) { p[e] = expf(acc[e] - mx); s += p[e]; }
        int best = 0; float bv = acc[0];
#pragma unroll
        for (int e = 1; e < 8; ++e) if (acc[e] > bv) { bv = acc[e]; best = e; }
        top1[t]  = best;
        score[t] = p[best] / s;
    }
}

// ---------------- deterministic per-expert reduce + tile table ----------------
__global__ void k_meta(const int* __restrict__ top1, const float* __restrict__ score,
                       int* __restrict__ mi, float* __restrict__ mf) {
    int wid = threadIdx.x >> 6, lane = threadIdx.x & 63;
    float s = 0.f; int c = 0;
    for (int t = lane; t < T_TOK; t += 64) {
        if (top1[t] == wid) { s += score[t]; c++; }
    }
    for (int o = 32; o; o >>= 1) { s += __shfl_down(s, o); c += __shfl_down(c, o); }
    __shared__ int   cs[8];
    __shared__ float ds[8];
    if (lane == 0) { cs[wid] = c; ds[wid] = s; }
    __syncthreads();
    if (threadIdx.x == 0) {
        int off = 0, nt = 0;
        for (int e = 0; e < 8; ++e) {
            mi[32 + e] = cs[e];
            mi[48 + e] = off;
            mi[16 + e] = off;                       // cursor
            mf[e]      = ds[e];
            mf[8 + e]  = (float)T_TOK / (ds[e] + EPSV);  // gscale
            int end = off + cs[e];
            for (int m = off; m < end; m += 128) {
                mi[64 + nt]  = e;    // tile expert
                mi[144 + nt] = m;    // tile slot start
                mi[224 + nt] = end;  // tile valid end
                nt++;
            }
            off = end;
        }
        mi[48 + 8] = off;
        mi[0] = nt;
    }
}

// ---------------- scatter tokens to expert-contiguous slots ----------------
__global__ __launch_bounds__(256) void k_scatter(const int* __restrict__ top1,
                                                 const float* __restrict__ score,
                                                 int* __restrict__ mi,
                                                 const float* __restrict__ mf,
                                                 int* __restrict__ perm,
                                                 float* __restrict__ coef) {
    int t = blockIdx.x * 256 + threadIdx.x;
    if (t >= T_TOK) return;
    int e = top1[t];
    int slot = atomicAdd(&mi[16 + e], 1);
    perm[slot] = t;
    coef[slot] = score[t] * mf[8 + e];
}

// ---------------- gather x rows into bf16, slot order ----------------
__global__ __launch_bounds__(256) void k_gatherX(const float* __restrict__ x,
                                                 const int* __restrict__ perm,
                                                 unsigned short* __restrict__ Xg) {
    int i = blockIdx.x * 256 + threadIdx.x;      // over T*128 chunks of 8
    int slot = i >> 7, ch = (i & 127) * 8;
    int t = perm[slot];
    const float4* px = (const float4*)(x + (size_t)t * D_DIM + ch);
    float4 a = px[0], b = px[1];
    union { unsigned short u[8]; uint4 v; } o;
    o.u[0] = f2bf(a.x); o.u[1] = f2bf(a.y); o.u[2] = f2bf(a.z); o.u[3] = f2bf(a.w);
    o.u[4] = f2bf(b.x); o.u[5] = f2bf(b.y); o.u[6] = f2bf(b.z); o.u[7] = f2bf(b.w);
    *(uint4*)(Xg + (size_t)slot * D_DIM + ch) = o.v;
}

// ---------------- transpose + cast weights: [E][R][C] f32 -> [E][C][R] bf16 ----------------
__global__ __launch_bounds__(256) void k_transp(const float* __restrict__ W,
                                                unsigned short* __restrict__ Wt,
                                                int R, int C) {
    __shared__ float tile[64][65];
    int e  = blockIdx.z;
    int c0 = blockIdx.x * 64, r0 = blockIdx.y * 64;
    int tr = threadIdx.x >> 6, tc = threadIdx.x & 63;
    const float* Win = W + ((size_t)e * R + r0) * C + c0;
#pragma unroll
    for (int it = 0; it < 16; ++it) {
        int r = it * 4 + tr;
        tile[r][tc] = Win[(size_t)r * C + tc];
    }
    __syncthreads();
    unsigned short* Wo = Wt + ((size_t)e * C + c0) * R + r0;
#pragma unroll
    for (int it = 0; it < 16; ++it) {
        int r = it * 4 + tr;
        Wo[(size_t)r * R + tc] = f2bf(tile[tc][r]);
    }
}

// ---------------- grouped GEMM, 128x128 tile, mfma_f32_16x16x32_bf16 ----------------
// MODE 0: C = relu(A @ Bt^T) -> H (bf16).   MODE 1: out[perm[row]] = coef[row] * (A @ Bt^T)
template <int MODE>
__global__ __launch_bounds__(256) void k_gemm(const unsigned short* __restrict__ A,
                                              const unsigned short* __restrict__ B,
                                              void* __restrict__ Cout,
                                              const int* __restrict__ mi,
                                              const int* __restrict__ perm,
                                              const float* __restrict__ coef,
                                              const int K_TOT, const int N_TOT) {
    __shared__ unsigned short As[128 * 32];
    __shared__ unsigned short Bs[128 * 32];
    const int numTiles = mi[0];
    const int tileIdx = blockIdx.y;
    if (tileIdx >= numTiles) return;
    const int e    = mi[64 + tileIdx];
    const int m0   = mi[144 + tileIdx];
    const int mend = mi[224 + tileIdx];
    const int n0   = blockIdx.x * 128;
    const int tid  = threadIdx.x;
    const int wid  = tid >> 6, lane = tid & 63;
    const int wr   = wid >> 1, wc = wid & 1;
    const unsigned short* Bexp = B + (size_t)e * N_TOT * K_TOT;

    const int ldRow  = lane >> 2;
    const int ldColB = (lane & 3) * 8;    // bf16 elems

    f32x4 acc[4][4];
#pragma unroll
    for (int m = 0; m < 4; ++m)
#pragma unroll
        for (int n = 0; n < 4; ++n) acc[m][n] = (f32x4){0.f, 0.f, 0.f, 0.f};

    const int fr = lane & 15, fq = lane >> 4;

    for (int k0 = 0; k0 < K_TOT; k0 += 32) {
#pragma unroll
        for (int q = 0; q < 2; ++q) {
            int r = wid * 32 + q * 16 + ldRow;
            const unsigned short* ga = A + (size_t)(m0 + r) * K_TOT + (k0 + ldColB);
            __builtin_amdgcn_global_load_lds((gvoid_t*)ga,
                                             (lvoid_t*)&As[(wid * 32 + q * 16) * 32],
                                             16, 0, 0);
            const unsigned short* gb = Bexp + (size_t)(n0 + r) * K_TOT + (k0 + ldColB);
            __builtin_amdgcn_global_load_lds((gvoid_t*)gb,
                                             (lvoid_t*)&Bs[(wid * 32 + q * 16) * 32],
                                             16, 0, 0);
        }
        __syncthreads();
        bf16x8 af[4], bfr[4];
#pragma unroll
        for (int m = 0; m < 4; ++m)
            af[m] = *reinterpret_cast<const bf16x8*>(&As[(wr * 64 + m * 16 + fr) * 32 + fq * 8]);
#pragma unroll
        for (int n = 0; n < 4; ++n)
            bfr[n] = *reinterpret_cast<const bf16x8*>(&Bs[(wc * 64 + n * 16 + fr) * 32 + fq * 8]);
#pragma unroll
        for (int m = 0; m < 4; ++m)
#pragma unroll
            for (int n = 0; n < 4; ++n)
                acc[m][n] = __builtin_amdgcn_mfma_f32_16x16x32_bf16(af[m], bfr[n], acc[m][n], 0, 0, 0);
        __syncthreads();
    }

    if (MODE == 0) {
        unsigned short* H = (unsigned short*)Cout;
#pragma unroll
        for (int m = 0; m < 4; ++m) {
            int rb = m0 + wr * 64 + m * 16 + fq * 4;
#pragma unroll
            for (int r = 0; r < 4; ++r) {
                int row = rb + r;
                if (row < mend) {
#pragma unroll
                    for (int n = 0; n < 4; ++n) {
                        int col = n0 + wc * 64 + n * 16 + fr;
                        float v = fmaxf(acc[m][n][r], 0.f);
                        H[(size_t)row * N_TOT + col] = f2bf(v);
                    }
                }
            }
        }
    } else {
        float* O = (float*)Cout;
#pragma unroll
        for (int m = 0; m < 4; ++m) {
            int rb = m0 + wr * 64 + m * 16 + fq * 4;
#pragma unroll
            for (int r = 0; r < 4; ++r) {
                int row = rb + r;
                if (row < mend) {
                    int   tkn = perm[row];
                    float cf  = coef[row];
#pragma unroll
                    for (int n = 0; n < 4; ++n) {
                        int col = n0 + wc * 64 + n * 16 + fr;
                        O[(size_t)tkn * N_TOT + col] = cf * acc[m][n][r];
                    }
                }
            }
        }
    }
}

extern "C" void kernel_launch(void* const* d_in, const int* in_sizes, int n_in,
                              void* d_out, int out_size, void* d_ws, size_t ws_size,
                              hipStream_t stream) {
    const float* x  = (const float*)d_in[0];
    const float* Wg = (const float*)d_in[1];
    const float* bg = (const float*)d_in[2];
    const float* W1 = (const float*)d_in[3];
    const float* W2 = (const float*)d_in[4];

    char* ws = (char*)d_ws;
    int*   mi    = (int*)ws;                         // meta ints (tile table, cursors)
    float* mf    = (float*)(ws + 2048);              // denom, gscale
    int*   top1  = (int*)(ws + 4096);
    float* score = (float*)(ws + 4096 + 32768);
    int*   perm  = (int*)(ws + 4096 + 2 * 32768);
    float* coef  = (float*)(ws + 4096 + 3 * 32768);
    unsigned short* Xg = (unsigned short*)(ws + 135168);     // (T+128) x 1024 bf16
    unsigned short* H  = (unsigned short*)(ws + 17174528);   // (T+128) x 4096 bf16
    unsigned short* Wt = (unsigned short*)(ws + 85331968);   // 8 x 4096 x 1024 bf16 (shared)

    k_gate<<<dim3(T_TOK / 4), dim3(256), 0, stream>>>(x, Wg, bg, top1, score);
    k_meta<<<dim3(1), dim3(512), 0, stream>>>(top1, score, mi, mf);
    k_scatter<<<dim3(T_TOK / 256), dim3(256), 0, stream>>>(top1, score, mi, mf, perm, coef);
    k_gatherX<<<dim3(T_TOK * 128 / 256), dim3(256), 0, stream>>>(x, perm, Xg);

    // W1: [8][1024][4096] f32 -> Wt [8][4096][1024] bf16
    k_transp<<<dim3(N_INNER / 64, D_DIM / 64, NEXP), dim3(256), 0, stream>>>(W1, Wt, D_DIM, N_INNER);
    // H = relu(Xg @ W1)
    k_gemm<0><<<dim3(N_INNER / 128, 72), dim3(256), 0, stream>>>(Xg, Wt, (void*)H, mi, perm, coef,
                                                                 D_DIM, N_INNER);
    // W2: [8][4096][1024] f32 -> Wt [8][1024][4096] bf16
    k_transp<<<dim3(D_DIM / 64, N_INNER / 64, NEXP), dim3(256), 0, stream>>>(W2, Wt, N_INNER, D_DIM);
    // out[perm[slot]] = coef[slot] * (H @ W2)
    k_gemm<1><<<dim3(D_DIM / 128, 72), dim3(256), 0, stream>>>(H, Wt, d_out, mi, perm, coef,
                                                               N_INNER, D_DIM);
}

// Round 2
// 454.206 us; speedup vs baseline: 1.0139x; 1.0139x over previous
//
#include <hip/hip_runtime.h>

#define D_DIM 1024
#define N_INNER 4096
#define NEXP 8
#define T_TOK 8192
#define EPSV 1e-6f

typedef __attribute__((ext_vector_type(4))) float f32x4;
typedef __bf16 bf16x8 __attribute__((ext_vector_type(8)));

typedef const __attribute__((address_space(1))) void gvoid_t;
typedef __attribute__((address_space(3))) void lvoid_t;

#define VMCNT(n) asm volatile("s_waitcnt vmcnt(" #n ")" ::: "memory")
#define SCHEDB() __builtin_amdgcn_sched_barrier(0)
#define BARRIER() do { SCHEDB(); __builtin_amdgcn_s_barrier(); } while (0)

static __device__ __forceinline__ unsigned short f2bf(float f) {
    unsigned int u = __float_as_uint(f);
    u = u + 0x7fffu + ((u >> 16) & 1u);   // round-to-nearest-even
    return (unsigned short)(u >> 16);
}

// ---------------- gating: one wave per token ----------------
__global__ __launch_bounds__(256) void k_gate(const float* __restrict__ x,
                                              const float* __restrict__ Wg,
                                              const float* __restrict__ bg,
                                              int* __restrict__ top1,
                                              float* __restrict__ score) {
    __shared__ float wgT[NEXP * D_DIM];
    int tid = threadIdx.x;
    for (int i = tid; i < NEXP * D_DIM; i += 256)
        wgT[(i & 7) * D_DIM + (i >> 3)] = Wg[i];
    __syncthreads();

    int wid = tid >> 6, lane = tid & 63;
    int t = blockIdx.x * 4 + wid;
    float acc[8] = {0.f, 0.f, 0.f, 0.f, 0.f, 0.f, 0.f, 0.f};
    const float* xp = x + (size_t)t * D_DIM + lane;
    for (int c = 0; c < D_DIM / 64; ++c) {
        float xv = xp[c * 64];
#pragma unroll
        for (int e = 0; e < 8; ++e) acc[e] += xv * wgT[e * D_DIM + c * 64 + lane];
    }
#pragma unroll
    for (int e = 0; e < 8; ++e) {
        float v = acc[e];
        for (int o = 32; o; o >>= 1) v += __shfl_xor(v, o);
        acc[e] = v;
    }
    if (lane == 0) {
        float mx = -1e30f;
#pragma unroll
        for (int e = 0; e < 8; ++e) { acc[e] += bg[e]; mx = fmaxf(mx, acc[e]); }
        float p[8], s = 0.f;
#pragma unroll
        for (int e = 0; e < 8; ++e) { p[e] = expf(acc[e] - mx); s += p[e]; }
        int best = 0; float bv = acc[0];
#pragma unroll
        for (int e = 1; e < 8; ++e) if (acc[e] > bv) { bv = acc[e]; best = e; }
        top1[t]  = best;
        score[t] = p[best] / s;
    }
}

// ---------------- deterministic per-expert reduce + tile tables ----------------
__global__ void k_meta(const int* __restrict__ top1, const float* __restrict__ score,
                       int* __restrict__ mi, float* __restrict__ mf) {
    int wid = threadIdx.x >> 6, lane = threadIdx.x & 63;
    float s = 0.f; int c = 0;
    for (int t = lane; t < T_TOK; t += 64) {
        if (top1[t] == wid) { s += score[t]; c++; }
    }
    for (int o = 32; o; o >>= 1) { s += __shfl_down(s, o); c += __shfl_down(c, o); }
    __shared__ int   cs[8];
    __shared__ float ds[8];
    if (lane == 0) { cs[wid] = c; ds[wid] = s; }
    __syncthreads();
    if (threadIdx.x == 0) {
        int off = 0, ntA = 0, ntB = 0;
        for (int e = 0; e < 8; ++e) {
            mi[16 + e] = off;                       // scatter cursor
            mf[e]      = ds[e];
            mf[8 + e]  = (float)T_TOK / (ds[e] + EPSV);
            int end = off + cs[e];
            for (int m = off; m < end; m += 256) {  // BM=256 table
                mi[64  + ntA] = e;
                mi[104 + ntA] = m;
                mi[144 + ntA] = end;
                ntA++;
            }
            for (int m = off; m < end; m += 128) {  // BM=128 table
                mi[184 + ntB] = e;
                mi[256 + ntB] = m;
                mi[328 + ntB] = end;
                ntB++;
            }
            off = end;
        }
        mi[0] = ntA;
        mi[1] = ntB;
    }
}

// ---------------- scatter tokens to expert-contiguous slots ----------------
__global__ __launch_bounds__(256) void k_scatter(const int* __restrict__ top1,
                                                 const float* __restrict__ score,
                                                 int* __restrict__ mi,
                                                 const float* __restrict__ mf,
                                                 int* __restrict__ perm,
                                                 float* __restrict__ coef) {
    int t = blockIdx.x * 256 + threadIdx.x;
    if (t >= T_TOK) return;
    int e = top1[t];
    int slot = atomicAdd(&mi[16 + e], 1);
    perm[slot] = t;
    coef[slot] = score[t] * mf[8 + e];
}

// ---------------- gather x rows into bf16, slot order ----------------
__global__ __launch_bounds__(256) void k_gatherX(const float* __restrict__ x,
                                                 const int* __restrict__ perm,
                                                 unsigned short* __restrict__ Xg) {
    int i = blockIdx.x * 256 + threadIdx.x;
    int slot = i >> 7, ch = (i & 127) * 8;
    int t = perm[slot];
    const float4* px = (const float4*)(x + (size_t)t * D_DIM + ch);
    float4 a = px[0], b = px[1];
    union { unsigned short u[8]; uint4 v; } o;
    o.u[0] = f2bf(a.x); o.u[1] = f2bf(a.y); o.u[2] = f2bf(a.z); o.u[3] = f2bf(a.w);
    o.u[4] = f2bf(b.x); o.u[5] = f2bf(b.y); o.u[6] = f2bf(b.z); o.u[7] = f2bf(b.w);
    *(uint4*)(Xg + (size_t)slot * D_DIM + ch) = o.v;
}

// ---------------- transpose + cast weights: [E][R][C] f32 -> [E][C][R] bf16 ----------------
__global__ __launch_bounds__(256) void k_transp(const float* __restrict__ W,
                                                unsigned short* __restrict__ Wt,
                                                int R, int C) {
    __shared__ float tile[64][65];
    int e  = blockIdx.z;
    int c0 = blockIdx.x * 64, r0 = blockIdx.y * 64;
    int tr = threadIdx.x >> 6, tc = threadIdx.x & 63;
    const float* Win = W + ((size_t)e * R + r0) * C + c0;
#pragma unroll
    for (int it = 0; it < 16; ++it) {
        int r = it * 4 + tr;
        tile[r][tc] = Win[(size_t)r * C + tc];
    }
    __syncthreads();
    unsigned short* Wo = Wt + ((size_t)e * C + c0) * R + r0;
#pragma unroll
    for (int it = 0; it < 16; ++it) {
        int r = it * 4 + tr;
        Wo[(size_t)r * R + tc] = f2bf(tile[tc][r]);
    }
}

// ============ deep-pipelined grouped GEMM ============
// BK=32, 4 LDS buffers (prefetch distance 3), 8 waves (2M x 4N), XOR-swizzled LDS.
// MODE 0: H = relu(A @ B^T)  (bf16 out).  MODE 1: out[perm[row]] = coef[row]*(A @ B^T) (f32 out).
template <int BM, int MODE>
__global__ __launch_bounds__(512, 2) void k_gemm8(const unsigned short* __restrict__ A,
                                                  const unsigned short* __restrict__ B,
                                                  void* __restrict__ Cout,
                                                  const int* __restrict__ mi,
                                                  const int* __restrict__ perm,
                                                  const float* __restrict__ coef,
                                                  const int K_TOT, const int N_TOT,
                                                  const int ntOff, const int expOff,
                                                  const int m0Off, const int mendOff) {
    extern __shared__ __align__(16) char smem[];
    constexpr int MF     = BM / 32;        // m-frags per wave (8 or 4)
    constexpr int MH     = MF / 2;         // frags per phase-half
    constexpr int ABYTES = BM * 64;        // A K-tile bytes (BM x 32 bf16)
    constexpr int BBYTES = 256 * 64;       // B K-tile bytes
    constexpr int BUFB   = ABYTES + BBYTES;
    constexpr int AQ     = BM / 128;       // A stage loads/thread (2 or 1)

    const int nt = mi[ntOff];
    const int ti = blockIdx.y;
    if (ti >= nt) return;
    const int e    = mi[expOff + ti];
    const int m0   = mi[m0Off + ti];
    const int mend = mi[mendOff + ti];
    const int n0   = blockIdx.x * 256;
    const int tid  = threadIdx.x;
    const int w    = tid >> 6, l = tid & 63;
    const int wr   = w >> 2, wc = w & 3;
    const int fr   = l & 15, fq = l >> 4;
    const int sel  = (fr >> 1) & 3;               // read-side swizzle selector
    const unsigned short* Bexp = B + (size_t)e * N_TOT * K_TOT;
    const int NK = K_TOT / 32;

    // stage source pointers (global side carries the inverse swizzle)
    const int gchunk = (l & 3) ^ ((l >> 3) & 3);
    const unsigned short* aSrc[AQ];
#pragma unroll
    for (int q = 0; q < AQ; ++q) {
        int rowT = q * 128 + w * 16 + (l >> 2);
        int rowG = m0 + rowT; if (rowG > T_TOK - 1) rowG = T_TOK - 1;   // clamp, no slack rows
        aSrc[q] = A + (size_t)rowG * K_TOT + gchunk * 8;
    }
    const unsigned short* bSrc[2];
#pragma unroll
    for (int q = 0; q < 2; ++q) {
        int rowT = q * 128 + w * 16 + (l >> 2);
        bSrc[q] = Bexp + (size_t)(n0 + rowT) * K_TOT + gchunk * 8;
    }

    auto stageA = [&](int kt) {
        char* base = smem + (kt & 3) * BUFB + w * 1024;
#pragma unroll
        for (int q = 0; q < AQ; ++q)
            __builtin_amdgcn_global_load_lds((gvoid_t*)(aSrc[q] + kt * 32),
                                             (lvoid_t*)(base + q * 8192), 16, 0, 0);
    };
    auto stageB = [&](int kt) {
        char* base = smem + (kt & 3) * BUFB + ABYTES + w * 1024;
#pragma unroll
        for (int q = 0; q < 2; ++q)
            __builtin_amdgcn_global_load_lds((gvoid_t*)(bSrc[q] + kt * 32),
                                             (lvoid_t*)(base + q * 8192), 16, 0, 0);
    };

    f32x4 acc[MF][4];
#pragma unroll
    for (int m = 0; m < MF; ++m)
#pragma unroll
        for (int n = 0; n < 4; ++n) acc[m][n] = (f32x4){0.f, 0.f, 0.f, 0.f};

    // prologue: stage K-tiles 0,1,2
    for (int kt = 0; kt < 3; ++kt) { stageA(kt); stageB(kt); }
    if constexpr (BM == 256) VMCNT(8); else VMCNT(6);
    BARRIER();

    const int aRowBase = wr * (BM / 2) + fr;
    const int bRowBase = wc * 64 + fr;

    for (int kt = 0; kt < NK; ++kt) {
        const char* buf = smem + (kt & 3) * BUFB;
        // ---- phase A: stage A(kt+3); read B-frags + A-mh0; MFMA mh0 ----
        if (kt + 3 < NK) stageA(kt + 3);
        bf16x8 bfr[4], af[MH];
#pragma unroll
        for (int n = 0; n < 4; ++n) {
            int row = bRowBase + n * 16;
            bfr[n] = *(const bf16x8*)(buf + ABYTES + row * 64 + (((fq ^ sel)) << 4));
        }
#pragma unroll
        for (int m = 0; m < MH; ++m) {
            int row = aRowBase + m * 16;
            af[m] = *(const bf16x8*)(buf + row * 64 + (((fq ^ sel)) << 4));
        }
        BARRIER();
        __builtin_amdgcn_s_setprio(1);
#pragma unroll
        for (int m = 0; m < MH; ++m)
#pragma unroll
            for (int n = 0; n < 4; ++n)
                acc[m][n] = __builtin_amdgcn_mfma_f32_16x16x32_bf16(af[m], bfr[n], acc[m][n], 0, 0, 0);
        __builtin_amdgcn_s_setprio(0);
        BARRIER();

        // ---- phase B: stage B(kt+3); read A-mh1; MFMA mh1 ----
        if (kt + 3 < NK) stageB(kt + 3);
        bf16x8 af2[MH];
#pragma unroll
        for (int m = 0; m < MH; ++m) {
            int row = aRowBase + (MH + m) * 16;
            af2[m] = *(const bf16x8*)(buf + row * 64 + (((fq ^ sel)) << 4));
        }
        BARRIER();
        __builtin_amdgcn_s_setprio(1);
#pragma unroll
        for (int m = 0; m < MH; ++m)
#pragma unroll
            for (int n = 0; n < 4; ++n)
                acc[MH + m][n] = __builtin_amdgcn_mfma_f32_16x16x32_bf16(af2[m], bfr[n], acc[MH + m][n], 0, 0, 0);
        __builtin_amdgcn_s_setprio(0);
        // counted vmcnt: keep 2 K-tiles of loads in flight, never drain to 0 mid-loop
        if (kt < NK - 3) {
            if constexpr (BM == 256) VMCNT(8); else VMCNT(6);
        } else if (kt == NK - 3) {
            if constexpr (BM == 256) VMCNT(4); else VMCNT(3);
        } else {
            VMCNT(0);
        }
        BARRIER();
    }

    // ---- epilogue ----
    if (MODE == 0) {
        unsigned short* H = (unsigned short*)Cout;
#pragma unroll
        for (int m = 0; m < MF; ++m) {
            int rb = m0 + wr * (BM / 2) + m * 16 + fq * 4;
#pragma unroll
            for (int r = 0; r < 4; ++r) {
                int row = rb + r;
                if (row < mend) {
#pragma unroll
                    for (int n = 0; n < 4; ++n) {
                        int col = n0 + wc * 64 + n * 16 + fr;
                        float v = fmaxf(acc[m][n][r], 0.f);
                        H[(size_t)row * N_TOT + col] = f2bf(v);
                    }
                }
            }
        }
    } else {
        float* O = (float*)Cout;
#pragma unroll
        for (int m = 0; m < MF; ++m) {
            int rb = m0 + wr * (BM / 2) + m * 16 + fq * 4;
#pragma unroll
            for (int r = 0; r < 4; ++r) {
                int row = rb + r;
                if (row < mend) {
                    int   tkn = perm[row];
                    float cf  = coef[row];
#pragma unroll
                    for (int n = 0; n < 4; ++n) {
                        int col = n0 + wc * 64 + n * 16 + fr;
                        O[(size_t)tkn * N_TOT + col] = cf * acc[m][n][r];
                    }
                }
            }
        }
    }
}

extern "C" void kernel_launch(void* const* d_in, const int* in_sizes, int n_in,
                              void* d_out, int out_size, void* d_ws, size_t ws_size,
                              hipStream_t stream) {
    const float* x  = (const float*)d_in[0];
    const float* Wg = (const float*)d_in[1];
    const float* bg = (const float*)d_in[2];
    const float* W1 = (const float*)d_in[3];
    const float* W2 = (const float*)d_in[4];

    char* ws = (char*)d_ws;
    int*   mi    = (int*)ws;
    float* mf    = (float*)(ws + 2048);
    int*   top1  = (int*)(ws + 4096);
    float* score = (float*)(ws + 36864);
    int*   perm  = (int*)(ws + 69632);
    float* coef  = (float*)(ws + 102400);
    unsigned short* Xg = (unsigned short*)(ws + 135168);     // 8192 x 1024 bf16
    unsigned short* H  = (unsigned short*)(ws + 16912384);   // 8192 x 4096 bf16
    unsigned short* Wt = (unsigned short*)(ws + 84021248);   // 8 x 4096 x 1024 bf16 (shared)

    hipFuncSetAttribute((const void*)&k_gemm8<256, 0>,
                        hipFuncAttributeMaxDynamicSharedMemorySize, 131072);
    hipFuncSetAttribute((const void*)&k_gemm8<128, 1>,
                        hipFuncAttributeMaxDynamicSharedMemorySize, 98304);

    k_gate<<<dim3(T_TOK / 4), dim3(256), 0, stream>>>(x, Wg, bg, top1, score);
    k_meta<<<dim3(1), dim3(512), 0, stream>>>(top1, score, mi, mf);
    k_scatter<<<dim3(T_TOK / 256), dim3(256), 0, stream>>>(top1, score, mi, mf, perm, coef);
    k_gatherX<<<dim3(T_TOK * 128 / 256), dim3(256), 0, stream>>>(x, perm, Xg);

    // W1: [8][1024][4096] f32 -> Wt [8][4096][1024] bf16
    k_transp<<<dim3(N_INNER / 64, D_DIM / 64, NEXP), dim3(256), 0, stream>>>(W1, Wt, D_DIM, N_INNER);
    // H = relu(Xg @ W1^T-layout), BM=256
    k_gemm8<256, 0><<<dim3(N_INNER / 256, 40), dim3(512), 131072, stream>>>(
        Xg, Wt, (void*)H, mi, perm, coef, D_DIM, N_INNER, 0, 64, 104, 144);
    // W2: [8][4096][1024] f32 -> Wt [8][1024][4096] bf16
    k_transp<<<dim3(D_DIM / 64, N_INNER / 64, NEXP), dim3(256), 0, stream>>>(W2, Wt, N_INNER, D_DIM);
    // out[perm[row]] = coef[row] * (H @ W2^T-layout), BM=128 (grid fill: ~284 blocks)
    k_gemm8<128, 1><<<dim3(D_DIM / 256, 72), dim3(512), 98304, stream>>>(
        H, Wt, d_out, mi, perm, coef, N_INNER, D_DIM, 1, 184, 256, 328);
}